// Round 10
// baseline (363.321 us; speedup 1.0000x reference)
//
#include <hip/hip_runtime.h>
#include <hip/hip_bf16.h>
#include <math.h>

#define BB 4
#define NN 4096
#define KK 32
#define HH 128

#define NPB 32        // nodes per block
#define THREADS 512   // 8 waves, 4 nodes per wave
#define NPI (NPB / 8) // nodes per wave

typedef short bf16x8 __attribute__((ext_vector_type(8)));
typedef float f32x16 __attribute__((ext_vector_type(16)));
typedef unsigned int u32;

// LDS map (73.5 KB -> 2 blocks/CU = 16 waves/CU = 4 waves/SIMD).
// No H0 buffer: layer-1 streams h0 per-ks into 4 live acc tiles, so the
// 128-VGPR budget (hard for 512-thread blocks on this hipcc, r4-r9) holds.
#define OFF_W1   0
#define OFF_W2   32768
#define OFF_SELF 65536                     // 32 nodes x 128 bf16 = 8192 B
#define OFF_WD   (OFF_SELF + NPB*HH*2)     // 256 B
#define OFF_B1   (OFF_WD + HH*2)           // 512 B (f32 b1)
#define OFF_B2   (OFF_B1 + HH*4)           // 512 B (f32 b2)
#define LDS_TOTAL (OFF_B2 + HH*4)          // 75264 B

#define MFMA(a,b,c) __builtin_amdgcn_mfma_f32_32x32x16_bf16(a,b,c,0,0,0)

__device__ __forceinline__ u32 pack_bf2(float lo, float hi) {
    __hip_bfloat162 h = __float22bfloat162_rn(make_float2(lo, hi));
    u32 r; __builtin_memcpy(&r, &h, 4); return r;
}
__device__ __forceinline__ short f2bfs(float v) {
    __hip_bfloat16 h = __float2bfloat16(v);
    short r; __builtin_memcpy(&r, &h, 2); return r;
}
__device__ __forceinline__ float bf2f(short s) {
    u32 u = ((u32)(unsigned short)s) << 16;
    float f; __builtin_memcpy(&f, &u, 4); return f;
}
// tanh-form GELU: max abs err ~3e-4 vs exact erf form (well under tolerance)
__device__ __forceinline__ float gelu_t(float x) {
    float x2 = x * x;
    float t = x * fmaf(0.10294828f, x2, 2.30220913f);  // 2u*log2(e)
    float e = exp2f(t);
    float r = __builtin_amdgcn_rcpf(e + 1.0f);
    return fmaf(-x, r, x);                              // x * (1 - 1/(e+1))
}

union frag { bf16x8 v; u32 w[4]; };

// layer-1 C tile (ACC, one mt) -> gelu+bias -> bf16 pairs -> F2[2mt],F2[2mt+1]
#define TRANS_MT(ACC, MT) do {                                                  \
    u32 pk8[8];                                                                 \
    _Pragma("unroll") for (int q = 0; q < 8; ++q) {                             \
        int row0 = 8 * (q >> 1) + 2 * (q & 1) + 4 * hi;                         \
        float2 bb = *(const float2*)(s_b1f + (MT) * 32 + row0);                 \
        pk8[q] = pack_bf2(gelu_t(ACC[2*q] + bb.x), gelu_t(ACC[2*q+1] + bb.y));  \
    }                                                                           \
    _Pragma("unroll") for (int e = 0; e < 2; ++e) {                             \
        const int ks_ = 2 * (MT) + e;                                           \
        _Pragma("unroll") for (int r = 0; r < 4; ++r) {                         \
            const int q0 = (r & 1) + 4 * e;                                     \
            u32 own  = hi ? pk8[q0 + 2] : pk8[q0];                              \
            u32 give = hi ? pk8[q0]     : pk8[q0 + 2];                          \
            u32 got  = (u32)__shfl_xor((int)give, 32, 64);                      \
            F2[ks_].w[r] = ((r >> 1) == hi) ? own : got;                        \
        }                                                                       \
    }                                                                           \
} while (0)

// ---------------------------------------------------------------------------
// Kernel A: Ysrc = bf16((enc*mask) @ W0[0:128]), Yself = bf16(.. @ W0[128:256] + b0)
// ---------------------------------------------------------------------------
__global__ __launch_bounds__(128) void precompute_kernel(
    const float* __restrict__ enc, const float* __restrict__ mask,
    const float* __restrict__ W0, const float* __restrict__ b0,
    __hip_bfloat16* __restrict__ Ysrc, __hip_bfloat16* __restrict__ Yself)
{
    const int tid = threadIdx.x;
    const int wave = tid >> 6;
    const int lane = tid & 63;
    const int li = lane & 31;
    const int hi = lane >> 5;
    const int rowBase = blockIdx.x * 64 + wave * 32;
    const int myrow = rowBase + li;

    const float m = mask[myrow];
    bf16x8 A[8];
    #pragma unroll
    for (int ks = 0; ks < 8; ++ks) {
        const float* p = enc + (size_t)myrow * HH + ks * 16 + hi * 8;
        float4 a = *(const float4*)p;
        float4 c = *(const float4*)(p + 4);
        frag f;
        f.w[0] = pack_bf2(a.x * m, a.y * m);
        f.w[1] = pack_bf2(a.z * m, a.w * m);
        f.w[2] = pack_bf2(c.x * m, c.y * m);
        f.w[3] = pack_bf2(c.z * m, c.w * m);
        A[ks] = f.v;
    }

    #pragma unroll
    for (int h2 = 0; h2 < 2; ++h2) {
        __hip_bfloat16* dest = h2 ? Yself : Ysrc;
        #pragma unroll 1
        for (int mt = 0; mt < 4; ++mt) {
            const float bias = h2 ? b0[mt * 32 + li] : 0.0f;
            f32x16 acc;
            #pragma unroll
            for (int r = 0; r < 16; ++r) acc[r] = 0.f;
            #pragma unroll
            for (int ks = 0; ks < 8; ++ks) {
                bf16x8 Bf;
                #pragma unroll
                for (int j = 0; j < 8; ++j) {
                    int k = ks * 16 + hi * 8 + j;
                    Bf[j] = f2bfs(W0[(size_t)(h2 * HH + k) * HH + mt * 32 + li]);
                }
                acc = MFMA(A[ks], Bf, acc);
            }
            #pragma unroll
            for (int r = 0; r < 16; ++r) {
                int rrow = (r & 3) + 8 * (r >> 2) + 4 * hi;
                dest[(size_t)(rowBase + rrow) * HH + mt * 32 + li] =
                    __float2bfloat16(acc[r] + bias);
            }
        }
    }
}

// ---------------------------------------------------------------------------
// Kernel B: per-edge MLP + masked mean. Layer-1 streams h0 per-ks into 4 live
// acc tiles (loop order swapped vs r8/r9) -> no H0 array in regs OR LDS.
// ---------------------------------------------------------------------------
__global__ __launch_bounds__(THREADS) void mpnn_kernel(
    const float* __restrict__ enc, const float* __restrict__ mask,
    const float* __restrict__ dist, const int* __restrict__ eidx,
    const __hip_bfloat16* __restrict__ Ysrc, const __hip_bfloat16* __restrict__ Yself,
    const float* __restrict__ W0,
    const float* __restrict__ W1, const float* __restrict__ b1,
    const float* __restrict__ W2, const float* __restrict__ b2,
    float* __restrict__ upd)
{
    extern __shared__ char lds[];
    const int tid  = threadIdx.x;
    const int wave = tid >> 6;
    const int lane = tid & 63;
    const int li   = lane & 31;
    const int hi   = lane >> 5;
    const int nodeBase = blockIdx.x * NPB;

    // ---- stage W1/W2 fragment tables (bf16, MFMA frag layout) ----
    #pragma unroll
    for (int tbl = 0; tbl < 2; ++tbl) {
        const float* W = tbl ? W2 : W1;
        short* dst = (short*)(lds + tbl * 32768);
        #pragma unroll
        for (int i = 0; i < (HH * HH) / THREADS; ++i) {
            int e = i * THREADS + tid;
            int feat = e & 127, k = e >> 7;
            float v = W[(size_t)k * HH + feat];
            int mt = feat >> 5, ks = k >> 4, h2 = (k >> 3) & 1, j = k & 7;
            dst[((mt * 8 + ks) * 64 + h2 * 32 + (feat & 31)) * 8 + j] = f2bfs(v);
        }
    }
    {
        uint4* sv = (uint4*)(lds + OFF_SELF);
        sv[tid] = *(const uint4*)(Yself + (size_t)nodeBase * HH + tid * 8);
    }
    short* swd = (short*)(lds + OFF_WD);
    if (tid < HH) swd[tid] = f2bfs(W0[(size_t)256 * HH + tid]);
    float* s_b1f = (float*)(lds + OFF_B1);
    if (tid < HH) s_b1f[tid] = b1[tid];
    float* s_b2f = (float*)(lds + OFF_B2);
    if (tid < HH) s_b2f[tid] = b2[tid];
    __syncthreads();

    const int b = nodeBase >> 12;
    const __hip_bfloat16* YsB = Ysrc + (size_t)b * NN * HH;

    #pragma unroll 1
    for (int i = 0; i < NPI; ++i) {
        const int node_local = wave * NPI + i;
        const int gnode = nodeBase + node_local;

        int ie = eidx[(size_t)gnode * KK + li];
        float dste = dist[(size_t)gnode * KK + li];
        float mask_n = mask[gnode];
        bool valid = ie >= 0;
        int ic = valid ? ie : 0;
        u32 vmask = (u32)__ballot(valid);
        int vc = __popc(vmask);
        float inv_vc = 1.0f / (float)(vc < 1 ? 1 : vc);

        const char* gbase = (const char*)(YsB + (size_t)ic * HH) + hi * 16;
        const short* sself = (const short*)(lds + OFF_SELF) + node_local * HH;

        // ---- layers 0+1 fused: per ks, h0 = gelu(gather+self+dist*wd) then
        //      4 MFMAs (one per mt tile); h0 is transient (4 regs) ----
        f32x16 a0, a1, a2, a3;
        #pragma unroll
        for (int r = 0; r < 16; ++r) { a0[r] = 0.f; a1[r] = 0.f; a2[r] = 0.f; a3[r] = 0.f; }
        #pragma unroll
        for (int ks = 0; ks < 8; ++ks) {
            bf16x8 g  = *(const bf16x8*)(gbase + ks * 32);
            bf16x8 ys = *(const bf16x8*)(sself + ks * 16 + hi * 8);
            bf16x8 wd = *(const bf16x8*)(swd + ks * 16 + hi * 8);
            frag h;
            #pragma unroll
            for (int q = 0; q < 4; ++q) {
                float f0 = gelu_t(bf2f(g[2*q])   + bf2f(ys[2*q])   + dste * bf2f(wd[2*q]));
                float f1 = gelu_t(bf2f(g[2*q+1]) + bf2f(ys[2*q+1]) + dste * bf2f(wd[2*q+1]));
                h.w[q] = pack_bf2(f0, f1);
            }
            a0 = MFMA(*(const bf16x8*)(lds + OFF_W1 + ((0 * 8 + ks) * 64 + lane) * 16), h.v, a0);
            a1 = MFMA(*(const bf16x8*)(lds + OFF_W1 + ((1 * 8 + ks) * 64 + lane) * 16), h.v, a1);
            a2 = MFMA(*(const bf16x8*)(lds + OFF_W1 + ((2 * 8 + ks) * 64 + lane) * 16), h.v, a2);
            a3 = MFMA(*(const bf16x8*)(lds + OFF_W1 + ((3 * 8 + ks) * 64 + lane) * 16), h.v, a3);
        }

        // ---- gelu+bias+pack+shuffle, one acc tile at a time (acc dies) ----
        frag F2[8];
        TRANS_MT(a0, 0);
        TRANS_MT(a1, 1);
        TRANS_MT(a2, 2);
        TRANS_MT(a3, 3);

        // ---- layer 2 (normal), one nt-tile at a time -> scalars ----
        float s0, s1, s2, s3;
        #pragma unroll
        for (int nt = 0; nt < 4; ++nt) {
            f32x16 acc;
            #pragma unroll
            for (int r = 0; r < 16; ++r) acc[r] = 0.f;
            #pragma unroll
            for (int ks = 0; ks < 8; ++ks) {
                bf16x8 w2f = *(const bf16x8*)(lds + OFF_W2 + ((nt * 8 + ks) * 64 + lane) * 16);
                acc = MFMA(F2[ks].v, w2f, acc);
            }
            float bv = s_b2f[nt * 32 + li];
            float t = 0.f;
            #pragma unroll
            for (int r = 0; r < 16; ++r) {
                float v = gelu_t(acc[r] + bv);
                int edge = (r & 3) + 8 * (r >> 2) + 4 * hi;
                t += ((vmask >> edge) & 1) ? v : 0.f;
            }
            t += __shfl_xor(t, 32, 64);
            if (nt == 0) s0 = t; else if (nt == 1) s1 = t;
            else if (nt == 2) s2 = t; else s3 = t;
        }

        // ---- epilogue: thread writes feats (hi*2)*32+li and (hi*2+1)*32+li ----
        float sa = hi ? s2 : s0;
        float sb = hi ? s3 : s1;
        int f0 = (hi * 2) * 32 + li;
        int f1 = (hi * 2 + 1) * 32 + li;
        float u0 = (enc[(size_t)gnode * HH + f0] + sa * inv_vc) * mask_n;
        float u1 = (enc[(size_t)gnode * HH + f1] + sb * inv_vc) * mask_n;
        upd[(size_t)gnode * HH + f0] = u0;
        upd[(size_t)gnode * HH + f1] = u1;
    }
}

// ---------------------------------------------------------------------------
// Kernel 2a: partial sums/sumsq over 128-row chunks -> (B,32,H)
// ---------------------------------------------------------------------------
#define RCHUNK 128
__global__ __launch_bounds__(128) void reduce_partial_kernel(
    const float* __restrict__ upd, float* __restrict__ psum, float* __restrict__ psumsq)
{
    const int blk = blockIdx.x;
    const int b = blk >> 5;
    const int p = blk & 31;
    const int j = threadIdx.x;
    const size_t base = ((size_t)b * NN + (size_t)p * RCHUNK) * HH + j;
    float s = 0.f, s2 = 0.f;
    #pragma unroll 4
    for (int r = 0; r < RCHUNK; ++r) {
        float v = upd[base + (size_t)r * HH];
        s += v;
        s2 = fmaf(v, v, s2);
    }
    psum[(size_t)blk * HH + j]   = s;
    psumsq[(size_t)blk * HH + j] = s2;
}

// ---------------------------------------------------------------------------
// Kernel 2b: combine partials -> mean, 1/std per (b, feature)
// ---------------------------------------------------------------------------
__global__ __launch_bounds__(128) void finalize_stats_kernel(
    const float* __restrict__ psum, const float* __restrict__ psumsq,
    const float* __restrict__ mask, float* __restrict__ meanp, float* __restrict__ istdp)
{
    const int b = blockIdx.x;
    const int j = threadIdx.x;
    float s = 0.f, s2 = 0.f;
    #pragma unroll 4
    for (int c = 0; c < 32; ++c) {
        s  += psum[((size_t)b * 32 + c) * HH + j];
        s2 += psumsq[((size_t)b * 32 + c) * HH + j];
    }
    float cpart = 0.f;
    #pragma unroll 4
    for (int t = 0; t < NN / HH; ++t)
        cpart += mask[(size_t)b * NN + (size_t)t * HH + j];
    __shared__ float red[HH];
    red[j] = cpart;
    __syncthreads();
    for (int off = HH / 2; off > 0; off >>= 1) {
        if (j < off) red[j] += red[j + off];
        __syncthreads();
    }
    float counts = red[0];
    if (counts == 0.f) counts = 1.f;
    float mean = s / counts;
    float var  = (s2 - 2.f * mean * s + (float)NN * mean * mean) / counts;
    meanp[b * HH + j] = mean;
    istdp[b * HH + j] = 1.0f / sqrtf(var + 1e-5f);
}

// ---------------------------------------------------------------------------
// Kernel 3: normalize out0 in place + write pass-through outputs
// ---------------------------------------------------------------------------
__global__ void write_out_kernel(
    const float* __restrict__ mask, const float* __restrict__ dist,
    const int* __restrict__ eidx, const float* __restrict__ meanp,
    const float* __restrict__ istdp, const float* __restrict__ scale,
    const float* __restrict__ shift, float* __restrict__ out)
{
    const size_t T0 = (size_t)BB * NN * HH;
    const size_t T1 = (size_t)BB * NN;
    const size_t T2 = (size_t)BB * NN * KK;
    const size_t stride = (size_t)gridDim.x * blockDim.x;
    const size_t t = (size_t)blockIdx.x * blockDim.x + threadIdx.x;

    for (size_t x = t; x < T0; x += stride) {
        int h = (int)(x & (HH - 1));
        size_t bn = x >> 7;
        int b = (int)(bn >> 12);
        float m = mask[bn];
        float v = (out[x] - meanp[b * HH + h]) * istdp[b * HH + h] * scale[h] + shift[h];
        out[x] = v * m;
    }
    float* out1 = out + T0;
    for (size_t x = t; x < T1; x += stride) out1[x] = mask[x];
    float* out2 = out1 + T1;
    for (size_t x = t; x < T2; x += stride) out2[x] = dist[x];
    float* out3 = out2 + T2;
    for (size_t x = t; x < T2; x += stride) out3[x] = (float)eidx[x];
}

// ---------------------------------------------------------------------------
extern "C" void kernel_launch(void* const* d_in, const int* in_sizes, int n_in,
                              void* d_out, int out_size, void* d_ws, size_t ws_size,
                              hipStream_t stream) {
    const float* enc   = (const float*)d_in[0];
    const float* mask  = (const float*)d_in[1];
    const float* dist  = (const float*)d_in[2];
    const int*   eidx  = (const int*)  d_in[3];
    const float* W0    = (const float*)d_in[4];
    const float* b0    = (const float*)d_in[5];
    const float* W1    = (const float*)d_in[6];
    const float* b1    = (const float*)d_in[7];
    const float* W2    = (const float*)d_in[8];
    const float* b2    = (const float*)d_in[9];
    const float* scale = (const float*)d_in[10];
    const float* shift = (const float*)d_in[11];
    float* out = (float*)d_out;
    float* upd = out;   // pre-norm upd lives in out[0:B*N*H], normalized in place later

    const size_t T0 = (size_t)BB * NN * HH;
    const size_t T1 = (size_t)BB * NN;

    __hip_bfloat16* Ysrc  = (__hip_bfloat16*)d_ws;                 // 4 MB
    __hip_bfloat16* Yself = (__hip_bfloat16*)(out + T0 + T1);      // 4 MB (out2/out3 region, overwritten last)
    float* wsf    = (float*)((char*)d_ws + (size_t)BB * NN * HH * 2);
    float* psum   = wsf;
    float* psumsq = psum + (size_t)BB * 32 * HH;
    float* meanp  = psumsq + (size_t)BB * 32 * HH;
    float* istdp  = meanp + (size_t)BB * HH;

    hipFuncSetAttribute((const void*)mpnn_kernel,
                        hipFuncAttributeMaxDynamicSharedMemorySize, LDS_TOTAL);

    precompute_kernel<<<dim3(256), dim3(128), 0, stream>>>(enc, mask, W0, b0, Ysrc, Yself);
    mpnn_kernel<<<dim3((BB * NN) / NPB), dim3(THREADS), LDS_TOTAL, stream>>>(
        enc, mask, dist, eidx, Ysrc, Yself, W0, W1, b1, W2, b2, upd);
    reduce_partial_kernel<<<dim3(BB * 32), dim3(128), 0, stream>>>(upd, psum, psumsq);
    finalize_stats_kernel<<<dim3(BB), dim3(128), 0, stream>>>(psum, psumsq, mask, meanp, istdp);
    write_out_kernel<<<dim3(1024), dim3(256), 0, stream>>>(
        mask, dist, eidx, meanp, istdp, scale, shift, out);
}

// Round 11
// 230.449 us; speedup vs baseline: 1.5766x; 1.5766x over previous
//
#include <hip/hip_runtime.h>
#include <hip/hip_bf16.h>
#include <math.h>

#define BB 4
#define NN 4096
#define KK 32
#define HH 128

#define NPB 32        // nodes per block
#define THREADS 512   // 8 waves, 4 nodes per wave
#define NPI (NPB / 8) // nodes per wave

typedef short bf16x8 __attribute__((ext_vector_type(8)));
typedef float f32x16 __attribute__((ext_vector_type(16)));
typedef unsigned int u32;

// LDS map (73.5 KB -> 2 blocks/CU = 16 waves/CU = 4 waves/SIMD).
// Streaming layer0+1 (no H0 array); ks loop is unroll-1 so the scheduler
// cannot hoist 8 iterations of gather/LDS loads over the live acc tiles
// (r10's full unroll did exactly that -> 263 MB scratch spill).
#define OFF_W1   0
#define OFF_W2   32768
#define OFF_SELF 65536                     // 32 nodes x 128 bf16 = 8192 B
#define OFF_WD   (OFF_SELF + NPB*HH*2)     // 256 B
#define OFF_B1   (OFF_WD + HH*2)           // 512 B (f32 b1)
#define OFF_B2   (OFF_B1 + HH*4)           // 512 B (f32 b2)
#define LDS_TOTAL (OFF_B2 + HH*4)          // 75264 B

#define MFMA(a,b,c) __builtin_amdgcn_mfma_f32_32x32x16_bf16(a,b,c,0,0,0)

__device__ __forceinline__ u32 pack_bf2(float lo, float hi) {
    __hip_bfloat162 h = __float22bfloat162_rn(make_float2(lo, hi));
    u32 r; __builtin_memcpy(&r, &h, 4); return r;
}
__device__ __forceinline__ short f2bfs(float v) {
    __hip_bfloat16 h = __float2bfloat16(v);
    short r; __builtin_memcpy(&r, &h, 2); return r;
}
__device__ __forceinline__ float bf2f(short s) {
    u32 u = ((u32)(unsigned short)s) << 16;
    float f; __builtin_memcpy(&f, &u, 4); return f;
}
// tanh-form GELU: max abs err ~3e-4 vs exact erf form (well under tolerance)
__device__ __forceinline__ float gelu_t(float x) {
    float x2 = x * x;
    float t = x * fmaf(0.10294828f, x2, 2.30220913f);  // 2u*log2(e)
    float e = exp2f(t);
    float r = __builtin_amdgcn_rcpf(e + 1.0f);
    return fmaf(-x, r, x);                              // x * (1 - 1/(e+1))
}

union frag { bf16x8 v; u32 w[4]; };

// layer-1 C tile (ACC, one mt) -> gelu+bias -> bf16 pairs -> F2[2mt],F2[2mt+1]
#define TRANS_MT(ACC, MT) do {                                                  \
    u32 pk8[8];                                                                 \
    _Pragma("unroll") for (int q = 0; q < 8; ++q) {                             \
        int row0 = 8 * (q >> 1) + 2 * (q & 1) + 4 * hi;                         \
        float2 bb = *(const float2*)(s_b1f + (MT) * 32 + row0);                 \
        pk8[q] = pack_bf2(gelu_t(ACC[2*q] + bb.x), gelu_t(ACC[2*q+1] + bb.y));  \
    }                                                                           \
    _Pragma("unroll") for (int e = 0; e < 2; ++e) {                             \
        const int ks_ = 2 * (MT) + e;                                           \
        _Pragma("unroll") for (int r = 0; r < 4; ++r) {                         \
            const int q0 = (r & 1) + 4 * e;                                     \
            u32 own  = hi ? pk8[q0 + 2] : pk8[q0];                              \
            u32 give = hi ? pk8[q0]     : pk8[q0 + 2];                          \
            u32 got  = (u32)__shfl_xor((int)give, 32, 64);                      \
            F2[ks_].w[r] = ((r >> 1) == hi) ? own : got;                        \
        }                                                                       \
    }                                                                           \
} while (0)

// ---------------------------------------------------------------------------
// Kernel A: Ysrc = bf16((enc*mask) @ W0[0:128]), Yself = bf16(.. @ W0[128:256] + b0)
// ---------------------------------------------------------------------------
__global__ __launch_bounds__(128) void precompute_kernel(
    const float* __restrict__ enc, const float* __restrict__ mask,
    const float* __restrict__ W0, const float* __restrict__ b0,
    __hip_bfloat16* __restrict__ Ysrc, __hip_bfloat16* __restrict__ Yself)
{
    const int tid = threadIdx.x;
    const int wave = tid >> 6;
    const int lane = tid & 63;
    const int li = lane & 31;
    const int hi = lane >> 5;
    const int rowBase = blockIdx.x * 64 + wave * 32;
    const int myrow = rowBase + li;

    const float m = mask[myrow];
    bf16x8 A[8];
    #pragma unroll
    for (int ks = 0; ks < 8; ++ks) {
        const float* p = enc + (size_t)myrow * HH + ks * 16 + hi * 8;
        float4 a = *(const float4*)p;
        float4 c = *(const float4*)(p + 4);
        frag f;
        f.w[0] = pack_bf2(a.x * m, a.y * m);
        f.w[1] = pack_bf2(a.z * m, a.w * m);
        f.w[2] = pack_bf2(c.x * m, c.y * m);
        f.w[3] = pack_bf2(c.z * m, c.w * m);
        A[ks] = f.v;
    }

    #pragma unroll
    for (int h2 = 0; h2 < 2; ++h2) {
        __hip_bfloat16* dest = h2 ? Yself : Ysrc;
        #pragma unroll 1
        for (int mt = 0; mt < 4; ++mt) {
            const float bias = h2 ? b0[mt * 32 + li] : 0.0f;
            f32x16 acc;
            #pragma unroll
            for (int r = 0; r < 16; ++r) acc[r] = 0.f;
            #pragma unroll
            for (int ks = 0; ks < 8; ++ks) {
                bf16x8 Bf;
                #pragma unroll
                for (int j = 0; j < 8; ++j) {
                    int k = ks * 16 + hi * 8 + j;
                    Bf[j] = f2bfs(W0[(size_t)(h2 * HH + k) * HH + mt * 32 + li]);
                }
                acc = MFMA(A[ks], Bf, acc);
            }
            #pragma unroll
            for (int r = 0; r < 16; ++r) {
                int rrow = (r & 3) + 8 * (r >> 2) + 4 * hi;
                dest[(size_t)(rowBase + rrow) * HH + mt * 32 + li] =
                    __float2bfloat16(acc[r] + bias);
            }
        }
    }
}

// ---------------------------------------------------------------------------
// Kernel B: per-edge MLP + masked mean. Layer0+1 fused, streaming per-ks with
// unroll-1 (no load hoisting over the 4 live acc tiles -> fits 128 VGPR).
// ---------------------------------------------------------------------------
__global__ __launch_bounds__(THREADS) void mpnn_kernel(
    const float* __restrict__ enc, const float* __restrict__ mask,
    const float* __restrict__ dist, const int* __restrict__ eidx,
    const __hip_bfloat16* __restrict__ Ysrc, const __hip_bfloat16* __restrict__ Yself,
    const float* __restrict__ W0,
    const float* __restrict__ W1, const float* __restrict__ b1,
    const float* __restrict__ W2, const float* __restrict__ b2,
    float* __restrict__ upd)
{
    extern __shared__ char lds[];
    const int tid  = threadIdx.x;
    const int wave = tid >> 6;
    const int lane = tid & 63;
    const int li   = lane & 31;
    const int hi   = lane >> 5;
    const int nodeBase = blockIdx.x * NPB;

    // ---- stage W1/W2 fragment tables (bf16, MFMA frag layout) ----
    #pragma unroll
    for (int tbl = 0; tbl < 2; ++tbl) {
        const float* W = tbl ? W2 : W1;
        short* dst = (short*)(lds + tbl * 32768);
        #pragma unroll
        for (int i = 0; i < (HH * HH) / THREADS; ++i) {
            int e = i * THREADS + tid;
            int feat = e & 127, k = e >> 7;
            float v = W[(size_t)k * HH + feat];
            int mt = feat >> 5, ks = k >> 4, h2 = (k >> 3) & 1, j = k & 7;
            dst[((mt * 8 + ks) * 64 + h2 * 32 + (feat & 31)) * 8 + j] = f2bfs(v);
        }
    }
    {
        uint4* sv = (uint4*)(lds + OFF_SELF);
        sv[tid] = *(const uint4*)(Yself + (size_t)nodeBase * HH + tid * 8);
    }
    short* swd = (short*)(lds + OFF_WD);
    if (tid < HH) swd[tid] = f2bfs(W0[(size_t)256 * HH + tid]);
    float* s_b1f = (float*)(lds + OFF_B1);
    if (tid < HH) s_b1f[tid] = b1[tid];
    float* s_b2f = (float*)(lds + OFF_B2);
    if (tid < HH) s_b2f[tid] = b2[tid];
    __syncthreads();

    const int b = nodeBase >> 12;
    const __hip_bfloat16* YsB = Ysrc + (size_t)b * NN * HH;

    #pragma unroll 1
    for (int i = 0; i < NPI; ++i) {
        const int node_local = wave * NPI + i;
        const int gnode = nodeBase + node_local;

        int ie = eidx[(size_t)gnode * KK + li];
        float dste = dist[(size_t)gnode * KK + li];
        float mask_n = mask[gnode];
        bool valid = ie >= 0;
        int ic = valid ? ie : 0;
        u32 vmask = (u32)__ballot(valid);
        int vc = __popc(vmask);
        float inv_vc = 1.0f / (float)(vc < 1 ? 1 : vc);

        const char* gbase = (const char*)(YsB + (size_t)ic * HH) + hi * 16;
        const short* sself = (const short*)(lds + OFF_SELF) + node_local * HH;

        // ---- layers 0+1 fused: per ks (UNROLL 1 - critical), h0 transient,
        //      4 MFMAs into 4 live acc tiles ----
        f32x16 a0, a1, a2, a3;
        #pragma unroll
        for (int r = 0; r < 16; ++r) { a0[r] = 0.f; a1[r] = 0.f; a2[r] = 0.f; a3[r] = 0.f; }
        #pragma unroll 1
        for (int ks = 0; ks < 8; ++ks) {
            bf16x8 g  = *(const bf16x8*)(gbase + ks * 32);
            bf16x8 ys = *(const bf16x8*)(sself + ks * 16 + hi * 8);
            bf16x8 wd = *(const bf16x8*)(swd + ks * 16 + hi * 8);
            frag h;
            #pragma unroll
            for (int q = 0; q < 4; ++q) {
                float f0 = gelu_t(bf2f(g[2*q])   + bf2f(ys[2*q])   + dste * bf2f(wd[2*q]));
                float f1 = gelu_t(bf2f(g[2*q+1]) + bf2f(ys[2*q+1]) + dste * bf2f(wd[2*q+1]));
                h.w[q] = pack_bf2(f0, f1);
            }
            const char* w1p = lds + OFF_W1 + (size_t)ks * 64 * 16 + (size_t)lane * 16;
            a0 = MFMA(*(const bf16x8*)(w1p),            h.v, a0);
            a1 = MFMA(*(const bf16x8*)(w1p +  8*64*16), h.v, a1);
            a2 = MFMA(*(const bf16x8*)(w1p + 16*64*16), h.v, a2);
            a3 = MFMA(*(const bf16x8*)(w1p + 24*64*16), h.v, a3);
        }

        // ---- gelu+bias+pack+shuffle, one acc tile at a time (acc dies) ----
        frag F2[8];
        TRANS_MT(a0, 0);
        TRANS_MT(a1, 1);
        TRANS_MT(a2, 2);
        TRANS_MT(a3, 3);

        // ---- layer 2 (normal), one nt-tile at a time -> scalars ----
        float s0, s1, s2, s3;
        #pragma unroll
        for (int nt = 0; nt < 4; ++nt) {
            f32x16 acc;
            #pragma unroll
            for (int r = 0; r < 16; ++r) acc[r] = 0.f;
            #pragma unroll
            for (int ks = 0; ks < 8; ++ks) {
                bf16x8 w2f = *(const bf16x8*)(lds + OFF_W2 + ((nt * 8 + ks) * 64 + lane) * 16);
                acc = MFMA(F2[ks].v, w2f, acc);
            }
            float bv = s_b2f[nt * 32 + li];
            float t = 0.f;
            #pragma unroll
            for (int r = 0; r < 16; ++r) {
                float v = gelu_t(acc[r] + bv);
                int edge = (r & 3) + 8 * (r >> 2) + 4 * hi;
                t += ((vmask >> edge) & 1) ? v : 0.f;
            }
            t += __shfl_xor(t, 32, 64);
            if (nt == 0) s0 = t; else if (nt == 1) s1 = t;
            else if (nt == 2) s2 = t; else s3 = t;
        }

        // ---- epilogue: thread writes feats (hi*2)*32+li and (hi*2+1)*32+li ----
        float sa = hi ? s2 : s0;
        float sb = hi ? s3 : s1;
        int f0 = (hi * 2) * 32 + li;
        int f1 = (hi * 2 + 1) * 32 + li;
        float u0 = (enc[(size_t)gnode * HH + f0] + sa * inv_vc) * mask_n;
        float u1 = (enc[(size_t)gnode * HH + f1] + sb * inv_vc) * mask_n;
        upd[(size_t)gnode * HH + f0] = u0;
        upd[(size_t)gnode * HH + f1] = u1;
    }
}

// ---------------------------------------------------------------------------
// Kernel 2a: partial sums/sumsq over 128-row chunks -> (B,32,H)
// ---------------------------------------------------------------------------
#define RCHUNK 128
__global__ __launch_bounds__(128) void reduce_partial_kernel(
    const float* __restrict__ upd, float* __restrict__ psum, float* __restrict__ psumsq)
{
    const int blk = blockIdx.x;
    const int b = blk >> 5;
    const int p = blk & 31;
    const int j = threadIdx.x;
    const size_t base = ((size_t)b * NN + (size_t)p * RCHUNK) * HH + j;
    float s = 0.f, s2 = 0.f;
    #pragma unroll 4
    for (int r = 0; r < RCHUNK; ++r) {
        float v = upd[base + (size_t)r * HH];
        s += v;
        s2 = fmaf(v, v, s2);
    }
    psum[(size_t)blk * HH + j]   = s;
    psumsq[(size_t)blk * HH + j] = s2;
}

// ---------------------------------------------------------------------------
// Kernel 2b: combine partials -> mean, 1/std per (b, feature)
// ---------------------------------------------------------------------------
__global__ __launch_bounds__(128) void finalize_stats_kernel(
    const float* __restrict__ psum, const float* __restrict__ psumsq,
    const float* __restrict__ mask, float* __restrict__ meanp, float* __restrict__ istdp)
{
    const int b = blockIdx.x;
    const int j = threadIdx.x;
    float s = 0.f, s2 = 0.f;
    #pragma unroll 4
    for (int c = 0; c < 32; ++c) {
        s  += psum[((size_t)b * 32 + c) * HH + j];
        s2 += psumsq[((size_t)b * 32 + c) * HH + j];
    }
    float cpart = 0.f;
    #pragma unroll 4
    for (int t = 0; t < NN / HH; ++t)
        cpart += mask[(size_t)b * NN + (size_t)t * HH + j];
    __shared__ float red[HH];
    red[j] = cpart;
    __syncthreads();
    for (int off = HH / 2; off > 0; off >>= 1) {
        if (j < off) red[j] += red[j + off];
        __syncthreads();
    }
    float counts = red[0];
    if (counts == 0.f) counts = 1.f;
    float mean = s / counts;
    float var  = (s2 - 2.f * mean * s + (float)NN * mean * mean) / counts;
    meanp[b * HH + j] = mean;
    istdp[b * HH + j] = 1.0f / sqrtf(var + 1e-5f);
}

// ---------------------------------------------------------------------------
// Kernel 3: normalize out0 in place + write pass-through outputs
// ---------------------------------------------------------------------------
__global__ void write_out_kernel(
    const float* __restrict__ mask, const float* __restrict__ dist,
    const int* __restrict__ eidx, const float* __restrict__ meanp,
    const float* __restrict__ istdp, const float* __restrict__ scale,
    const float* __restrict__ shift, float* __restrict__ out)
{
    const size_t T0 = (size_t)BB * NN * HH;
    const size_t T1 = (size_t)BB * NN;
    const size_t T2 = (size_t)BB * NN * KK;
    const size_t stride = (size_t)gridDim.x * blockDim.x;
    const size_t t = (size_t)blockIdx.x * blockDim.x + threadIdx.x;

    for (size_t x = t; x < T0; x += stride) {
        int h = (int)(x & (HH - 1));
        size_t bn = x >> 7;
        int b = (int)(bn >> 12);
        float m = mask[bn];
        float v = (out[x] - meanp[b * HH + h]) * istdp[b * HH + h] * scale[h] + shift[h];
        out[x] = v * m;
    }
    float* out1 = out + T0;
    for (size_t x = t; x < T1; x += stride) out1[x] = mask[x];
    float* out2 = out1 + T1;
    for (size_t x = t; x < T2; x += stride) out2[x] = dist[x];
    float* out3 = out2 + T2;
    for (size_t x = t; x < T2; x += stride) out3[x] = (float)eidx[x];
}

// ---------------------------------------------------------------------------
extern "C" void kernel_launch(void* const* d_in, const int* in_sizes, int n_in,
                              void* d_out, int out_size, void* d_ws, size_t ws_size,
                              hipStream_t stream) {
    const float* enc   = (const float*)d_in[0];
    const float* mask  = (const float*)d_in[1];
    const float* dist  = (const float*)d_in[2];
    const int*   eidx  = (const int*)  d_in[3];
    const float* W0    = (const float*)d_in[4];
    const float* b0    = (const float*)d_in[5];
    const float* W1    = (const float*)d_in[6];
    const float* b1    = (const float*)d_in[7];
    const float* W2    = (const float*)d_in[8];
    const float* b2    = (const float*)d_in[9];
    const float* scale = (const float*)d_in[10];
    const float* shift = (const float*)d_in[11];
    float* out = (float*)d_out;
    float* upd = out;   // pre-norm upd lives in out[0:B*N*H], normalized in place later

    const size_t T0 = (size_t)BB * NN * HH;
    const size_t T1 = (size_t)BB * NN;

    __hip_bfloat16* Ysrc  = (__hip_bfloat16*)d_ws;                 // 4 MB
    __hip_bfloat16* Yself = (__hip_bfloat16*)(out + T0 + T1);      // 4 MB (out2/out3 region, overwritten last)
    float* wsf    = (float*)((char*)d_ws + (size_t)BB * NN * HH * 2);
    float* psum   = wsf;
    float* psumsq = psum + (size_t)BB * 32 * HH;
    float* meanp  = psumsq + (size_t)BB * 32 * HH;
    float* istdp  = meanp + (size_t)BB * HH;

    hipFuncSetAttribute((const void*)mpnn_kernel,
                        hipFuncAttributeMaxDynamicSharedMemorySize, LDS_TOTAL);

    precompute_kernel<<<dim3(256), dim3(128), 0, stream>>>(enc, mask, W0, b0, Ysrc, Yself);
    mpnn_kernel<<<dim3((BB * NN) / NPB), dim3(THREADS), LDS_TOTAL, stream>>>(
        enc, mask, dist, eidx, Ysrc, Yself, W0, W1, b1, W2, b2, upd);
    reduce_partial_kernel<<<dim3(BB * 32), dim3(128), 0, stream>>>(upd, psum, psumsq);
    finalize_stats_kernel<<<dim3(BB), dim3(128), 0, stream>>>(psum, psumsq, mask, meanp, istdp);
    write_out_kernel<<<dim3(1024), dim3(256), 0, stream>>>(
        mask, dist, eidx, meanp, istdp, scale, shift, out);
}